// Round 1
// baseline (152804.175 us; speedup 1.0000x reference)
//
#include <hip/hip_runtime.h>
#include <cstddef>

// Decoder: B=64, T=512, I=512, H1=256, H2=128, C=1024, M=80, L=2
// Baseline structure: 6 kernels per timestep, 512 timesteps, all on `stream`.
// Activations live in d_ws with [dim][batch] layout (batch contiguous) so that
// lane==batch loads are coalesced. Weight rows are read wave-uniform (64-lane
// broadcast) as float4. Hidden states are double-buffered across timesteps.

namespace {

constexpr int kB = 64, kT = 512, kI = 512, kH1 = 256, kH2 = 128, kC = 1024, kM = 80;

__device__ __forceinline__ float sigm(float x) { return 1.0f / (1.0f + __expf(-x)); }
__device__ __forceinline__ float tanh_(float x) {
  float a = fabsf(x);
  float e = __expf(-2.0f * a);
  float r = (1.0f - e) / (1.0f + e);
  return copysignf(r, x);
}

// prenet layer 0: h_pre[j][b] = relu(b0[j] + sum_m w0[j][m] * frame[b][m])
// frame comes from d_out at timestep t-1 (zeros at t==0).
__global__ __launch_bounds__(256) void k_prenet0(const float* __restrict__ out_frames, int t,
    const float* __restrict__ w0, const float* __restrict__ b0, float* __restrict__ h_pre) {
  int b = threadIdx.x;                 // 0..63 (lane)
  int j = blockIdx.x * 4 + threadIdx.y; // 0..255
  float acc = b0[j];
  if (t > 0) {
    const float* fr = out_frames + (size_t)b * (kT * kM) + (size_t)(t - 1) * kM;
    const float* w = w0 + (size_t)j * kM;
#pragma unroll 8
    for (int m = 0; m < kM; ++m) acc = fmaf(w[m], fr[m], acc);
  }
  h_pre[j * kB + b] = fmaxf(acc, 0.0f);
}

// prenet layer 1: p[j][b] = relu(b1[j] + sum_k w1[j][k] * h_pre[k][b])
__global__ __launch_bounds__(256) void k_prenet1(const float* __restrict__ h_pre,
    const float* __restrict__ w1, const float* __restrict__ b1, float* __restrict__ p) {
  int b = threadIdx.x;
  int j = blockIdx.x * 4 + threadIdx.y; // 0..127
  float acc = b1[j];
  const float4* w4 = (const float4*)(w1 + (size_t)j * kH1);
  for (int k4 = 0; k4 < kH1 / 4; ++k4) {
    int k = k4 * 4;
    float4 w = w4[k4];
    acc += w.x * h_pre[(k + 0) * kB + b] + w.y * h_pre[(k + 1) * kB + b] +
           w.z * h_pre[(k + 2) * kB + b] + w.w * h_pre[(k + 3) * kB + b];
  }
  p[j * kB + b] = fmaxf(acc, 0.0f);
}

// attention GRU cell: x = concat(feat_t[b, 0:512], p[b, 0:128]) (K = 640)
// gates [r|z|n] row blocks of w_ih[3072][640], w_hh[3072][1024].
__global__ __launch_bounds__(256) void k_gru_attn(const float* __restrict__ inputs, int t,
    const float* __restrict__ p, const float* __restrict__ h_cur,
    const float* __restrict__ w_ih, const float* __restrict__ w_hh,
    const float* __restrict__ b_ih, const float* __restrict__ b_hh,
    float* __restrict__ h_nxt) {
  int b = threadIdx.x;
  int c = blockIdx.x * 4 + threadIdx.y; // 0..1023
  const float* feat = inputs + (size_t)b * (kT * kI) + (size_t)t * kI;

  float ir = b_ih[c], iz = b_ih[c + kC], in_ = b_ih[c + 2 * kC];
  const float4* wr4 = (const float4*)(w_ih + (size_t)c * 640);
  const float4* wz4 = (const float4*)(w_ih + (size_t)(c + kC) * 640);
  const float4* wn4 = (const float4*)(w_ih + (size_t)(c + 2 * kC) * 640);
  const float4* f4 = (const float4*)feat;
  // feat part (per-lane sequential rows; L1-cached)
  for (int k4 = 0; k4 < kI / 4; ++k4) {
    float4 x = f4[k4];
    float4 a = wr4[k4];
    ir += a.x * x.x + a.y * x.y + a.z * x.z + a.w * x.w;
    a = wz4[k4];
    iz += a.x * x.x + a.y * x.y + a.z * x.z + a.w * x.w;
    a = wn4[k4];
    in_ += a.x * x.x + a.y * x.y + a.z * x.z + a.w * x.w;
  }
  // prenet part (coalesced activation loads)
  for (int k4 = 0; k4 < kH2 / 4; ++k4) {
    int k = k4 * 4;
    float x0 = p[(k + 0) * kB + b], x1 = p[(k + 1) * kB + b];
    float x2 = p[(k + 2) * kB + b], x3 = p[(k + 3) * kB + b];
    float4 a = wr4[kI / 4 + k4];
    ir += a.x * x0 + a.y * x1 + a.z * x2 + a.w * x3;
    a = wz4[kI / 4 + k4];
    iz += a.x * x0 + a.y * x1 + a.z * x2 + a.w * x3;
    a = wn4[kI / 4 + k4];
    in_ += a.x * x0 + a.y * x1 + a.z * x2 + a.w * x3;
  }

  float hr = b_hh[c], hz = b_hh[c + kC], hn = b_hh[c + 2 * kC];
  const float4* vr4 = (const float4*)(w_hh + (size_t)c * kC);
  const float4* vz4 = (const float4*)(w_hh + (size_t)(c + kC) * kC);
  const float4* vn4 = (const float4*)(w_hh + (size_t)(c + 2 * kC) * kC);
  for (int k4 = 0; k4 < kC / 4; ++k4) {
    int k = k4 * 4;
    float h0 = h_cur[(k + 0) * kB + b], h1 = h_cur[(k + 1) * kB + b];
    float h2 = h_cur[(k + 2) * kB + b], h3 = h_cur[(k + 3) * kB + b];
    float4 a = vr4[k4];
    hr += a.x * h0 + a.y * h1 + a.z * h2 + a.w * h3;
    a = vz4[k4];
    hz += a.x * h0 + a.y * h1 + a.z * h2 + a.w * h3;
    a = vn4[k4];
    hn += a.x * h0 + a.y * h1 + a.z * h2 + a.w * h3;
  }

  float hold = h_cur[c * kB + b];
  float r = sigm(ir + hr), z = sigm(iz + hz);
  float n = tanh_(in_ + r * hn);
  h_nxt[c * kB + b] = (1.0f - z) * n + z * hold;
}

// residual GRU layer: h' = GRUCell(x, h); x_out = x + h'
__global__ __launch_bounds__(256) void k_gru_res(const float* __restrict__ x_in,
    const float* __restrict__ h_cur,
    const float* __restrict__ w_ih, const float* __restrict__ w_hh,
    const float* __restrict__ b_ih, const float* __restrict__ b_hh,
    float* __restrict__ h_nxt, float* __restrict__ x_out) {
  int b = threadIdx.x;
  int c = blockIdx.x * 4 + threadIdx.y; // 0..1023
  float ir = b_ih[c], iz = b_ih[c + kC], in_ = b_ih[c + 2 * kC];
  float hr = b_hh[c], hz = b_hh[c + kC], hn = b_hh[c + 2 * kC];
  const float4* ar4 = (const float4*)(w_ih + (size_t)c * kC);
  const float4* az4 = (const float4*)(w_ih + (size_t)(c + kC) * kC);
  const float4* an4 = (const float4*)(w_ih + (size_t)(c + 2 * kC) * kC);
  const float4* vr4 = (const float4*)(w_hh + (size_t)c * kC);
  const float4* vz4 = (const float4*)(w_hh + (size_t)(c + kC) * kC);
  const float4* vn4 = (const float4*)(w_hh + (size_t)(c + 2 * kC) * kC);
  for (int k4 = 0; k4 < kC / 4; ++k4) {
    int k = k4 * 4;
    float x0 = x_in[(k + 0) * kB + b], x1 = x_in[(k + 1) * kB + b];
    float x2 = x_in[(k + 2) * kB + b], x3 = x_in[(k + 3) * kB + b];
    float4 a = ar4[k4];
    ir += a.x * x0 + a.y * x1 + a.z * x2 + a.w * x3;
    a = az4[k4];
    iz += a.x * x0 + a.y * x1 + a.z * x2 + a.w * x3;
    a = an4[k4];
    in_ += a.x * x0 + a.y * x1 + a.z * x2 + a.w * x3;
    float h0 = h_cur[(k + 0) * kB + b], h1 = h_cur[(k + 1) * kB + b];
    float h2 = h_cur[(k + 2) * kB + b], h3 = h_cur[(k + 3) * kB + b];
    a = vr4[k4];
    hr += a.x * h0 + a.y * h1 + a.z * h2 + a.w * h3;
    a = vz4[k4];
    hz += a.x * h0 + a.y * h1 + a.z * h2 + a.w * h3;
    a = vn4[k4];
    hn += a.x * h0 + a.y * h1 + a.z * h2 + a.w * h3;
  }
  float xv = x_in[c * kB + b];
  float hold = h_cur[c * kB + b];
  float r = sigm(ir + hr), z = sigm(iz + hz);
  float n = tanh_(in_ + r * hn);
  float hnew = (1.0f - z) * n + z * hold;
  h_nxt[c * kB + b] = hnew;
  x_out[c * kB + b] = xv + hnew;
}

// projection: out[b][t][m] = pb[m] + sum_k pw[m][k] * x2[k][b]
__global__ __launch_bounds__(256) void k_proj(const float* __restrict__ x2,
    const float* __restrict__ pw, const float* __restrict__ pb,
    float* __restrict__ out, int t) {
  int b = threadIdx.x;
  int m = blockIdx.x * 4 + threadIdx.y; // 0..79
  float acc = pb[m];
  const float4* w4 = (const float4*)(pw + (size_t)m * kC);
  for (int k4 = 0; k4 < kC / 4; ++k4) {
    int k = k4 * 4;
    float4 w = w4[k4];
    acc += w.x * x2[(k + 0) * kB + b] + w.y * x2[(k + 1) * kB + b] +
           w.z * x2[(k + 2) * kB + b] + w.w * x2[(k + 3) * kB + b];
  }
  out[(size_t)b * (kT * kM) + (size_t)t * kM + m] = acc;
}

} // namespace

extern "C" void kernel_launch(void* const* d_in, const int* in_sizes, int n_in,
                              void* d_out, int out_size, void* d_ws, size_t ws_size,
                              hipStream_t stream) {
  const float* inputs   = (const float*)d_in[0];
  const float* pre_w0   = (const float*)d_in[1];
  const float* pre_b0   = (const float*)d_in[2];
  const float* pre_w1   = (const float*)d_in[3];
  const float* pre_b1   = (const float*)d_in[4];
  const float* attn_wih = (const float*)d_in[5];
  const float* attn_whh = (const float*)d_in[6];
  const float* attn_bih = (const float*)d_in[7];
  const float* attn_bhh = (const float*)d_in[8];
  const float* gru_wih  = (const float*)d_in[9];   // [2][3072][1024]
  const float* gru_whh  = (const float*)d_in[10];  // [2][3072][1024]
  const float* gru_bih  = (const float*)d_in[11];  // [2][3072]
  const float* gru_bhh  = (const float*)d_in[12];  // [2][3072]
  const float* proj_w   = (const float*)d_in[13];  // [80][1024]
  const float* proj_b   = (const float*)d_in[14];  // [80]
  float* out = (float*)d_out;
  float* ws = (float*)d_ws;

  const int HB = kC * kB; // 65536 floats per [1024][64] buffer
  // layout: hA0 h1_0 h2_0 | hA1 h1_1 h2_1 | x1 x2 | h_pre p
  float* hA[2] = { ws + 0 * HB, ws + 3 * HB };
  float* h1[2] = { ws + 1 * HB, ws + 4 * HB };
  float* h2[2] = { ws + 2 * HB, ws + 5 * HB };
  float* x1    = ws + 6 * HB;
  float* x2    = ws + 7 * HB;
  float* h_pre = ws + 8 * HB;            // [256][64]
  float* p     = h_pre + kH1 * kB;       // [128][64]

  // zero initial hidden states (buffers 0 are the t=0 inputs)
  hipMemsetAsync(ws, 0, (size_t)3 * HB * sizeof(float), stream);

  dim3 blk(64, 4, 1);
  const float* g_wih1 = gru_wih + (size_t)3 * kC * kC;
  const float* g_whh1 = gru_whh + (size_t)3 * kC * kC;
  const float* g_bih1 = gru_bih + 3 * kC;
  const float* g_bhh1 = gru_bhh + 3 * kC;

  for (int t = 0; t < kT; ++t) {
    int cur = t & 1, nxt = cur ^ 1;
    k_prenet0<<<kH1 / 4, blk, 0, stream>>>(out, t, pre_w0, pre_b0, h_pre);
    k_prenet1<<<kH2 / 4, blk, 0, stream>>>(h_pre, pre_w1, pre_b1, p);
    k_gru_attn<<<kC / 4, blk, 0, stream>>>(inputs, t, p, hA[cur],
                                           attn_wih, attn_whh, attn_bih, attn_bhh, hA[nxt]);
    k_gru_res<<<kC / 4, blk, 0, stream>>>(hA[nxt], h1[cur],
                                          gru_wih, gru_whh, gru_bih, gru_bhh, h1[nxt], x1);
    k_gru_res<<<kC / 4, blk, 0, stream>>>(x1, h2[cur],
                                          g_wih1, g_whh1, g_bih1, g_bhh1, h2[nxt], x2);
    k_proj<<<kM / 4, blk, 0, stream>>>(x2, proj_w, proj_b, out, t);
  }
}

// Round 2
// 59676.691 us; speedup vs baseline: 2.5605x; 2.5605x over previous
//
#include <hip/hip_runtime.h>
#include <cstddef>

// Decoder: B=64, T=512, I=512, H1=256, H2=128, C=1024, M=80, L=2
// Round 2: bf16 MFMA for the 3 big GRU matmuls. Weights repacked once per
// launch into d_ws in MFMA fragment order (coalesced dwordx4 A-loads).
// Recurrent h kept in fp32 for the gate blend; bf16 copies feed the MFMA.

namespace {

constexpr int kB = 64, kT = 512, kI = 512, kH1 = 256, kH2 = 128, kC = 1024, kM = 80;

typedef __attribute__((ext_vector_type(8))) __bf16 bf16x8;
typedef __attribute__((ext_vector_type(4))) float f32x4;

__device__ __forceinline__ float sigm(float x) { return 1.0f / (1.0f + __expf(-x)); }
__device__ __forceinline__ float tanh_(float x) {
  float a = fabsf(x);
  float e = __expf(-2.0f * a);
  float r = (1.0f - e) / (1.0f + e);
  return copysignf(r, x);
}
__device__ __forceinline__ unsigned short f2bf(float x) {
  unsigned u = __builtin_bit_cast(unsigned, x);
  u += 0x7fffu + ((u >> 16) & 1u);   // RNE
  return (unsigned short)(u >> 16);
}

// ---------------- weight repack: fp32 [row][col] -> bf16 frag order ----------
// dst frag layout: [rt][ks][lane][8]; row = row0 + rt*16 + (lane&15),
// k = ks*32 + (lane>>4)*8 + j.  Columns < K1 come from srcA, else srcB.
__global__ __launch_bounds__(256) void k_build_frags(
    const float* __restrict__ srcA, int ldA,
    const float* __restrict__ srcB, int ldB,
    int row0, int K1, int nks, unsigned short* __restrict__ dst) {
  int idx = blockIdx.x * 256 + threadIdx.x;
  int lane = idx & 63;
  int ks = (idx >> 6) % nks;
  int rt = idx / (64 * nks);
  if (rt >= 64) return;
  int row = row0 + rt * 16 + (lane & 15);
  int kk = ks * 32 + ((lane >> 4) & 3) * 8;
  const float* s = (kk < K1) ? (srcA + (size_t)row * ldA + kk)
                             : (srcB + (size_t)row * ldB + (kk - K1));
  unsigned short* d = dst + ((size_t)(rt * nks + ks) * 64 + lane) * 8;
#pragma unroll
  for (int j = 0; j < 8; ++j) d[j] = f2bf(s[j]);
}

// ---------------- small fp32 kernels ----------------------------------------
__global__ __launch_bounds__(256) void k_prenet0(const float* __restrict__ out_frames, int t,
    const float* __restrict__ w0, const float* __restrict__ b0, float* __restrict__ h_pre) {
  int b = threadIdx.x;
  int j = blockIdx.x * 4 + threadIdx.y;
  float acc = b0[j];
  if (t > 0) {
    const float* fr = out_frames + (size_t)b * (kT * kM) + (size_t)(t - 1) * kM;
    const float* w = w0 + (size_t)j * kM;
#pragma unroll 8
    for (int m = 0; m < kM; ++m) acc = fmaf(w[m], fr[m], acc);
  }
  h_pre[j * kB + b] = fmaxf(acc, 0.0f);
}

__global__ __launch_bounds__(256) void k_prenet1(const float* __restrict__ h_pre,
    const float* __restrict__ w1, const float* __restrict__ b1,
    unsigned short* __restrict__ p_bf16) {
  int b = threadIdx.x;
  int j = blockIdx.x * 4 + threadIdx.y; // 0..127
  float acc = b1[j];
  const float4* w4 = (const float4*)(w1 + (size_t)j * kH1);
  for (int k4 = 0; k4 < kH1 / 4; ++k4) {
    int k = k4 * 4;
    float4 w = w4[k4];
    acc += w.x * h_pre[(k + 0) * kB + b] + w.y * h_pre[(k + 1) * kB + b] +
           w.z * h_pre[(k + 2) * kB + b] + w.w * h_pre[(k + 3) * kB + b];
  }
  p_bf16[(size_t)b * kH2 + j] = f2bf(fmaxf(acc, 0.0f));
}

__global__ __launch_bounds__(256) void k_proj(const float* __restrict__ x2,
    const float* __restrict__ pw, const float* __restrict__ pb,
    float* __restrict__ out, int t) {
  int b = threadIdx.x;
  int m = blockIdx.x * 4 + threadIdx.y; // 0..79
  float acc = pb[m];
  const float4* w4 = (const float4*)(pw + (size_t)m * kC);
  for (int k4 = 0; k4 < kC / 4; ++k4) {
    int k = k4 * 4;
    float4 w = w4[k4];
    acc += w.x * x2[(k + 0) * kB + b] + w.y * x2[(k + 1) * kB + b] +
           w.z * x2[(k + 2) * kB + b] + w.w * x2[(k + 3) * kB + b];
  }
  out[(size_t)b * (kT * kM) + (size_t)t * kM + m] = acc;
}

// ---------------- MFMA GRU kernels ------------------------------------------
// Each block: 16 output channels x 64 batch; 4 waves = 4 batch sub-tiles of 16.
// A frags: [rt][ks][lane] * 16B, fully coalesced per wave.
// B frags: activation [b][k] bf16, 16B contiguous per lane.

// residual GRU: B = xcat[b][2048] = [x | h]; K = 2048 (64 ks).
__global__ __launch_bounds__(256) void k_res_mfma(
    const unsigned short* __restrict__ Ar, const unsigned short* __restrict__ Az,
    const unsigned short* __restrict__ An,
    const unsigned short* __restrict__ xcat_in,  // [64][2048] bf16
    const float* __restrict__ xin_f32,           // [1024][64] residual input x
    const float* __restrict__ h_old,             // [1024][64]
    const float* __restrict__ bih, const float* __restrict__ bhh,
    float* __restrict__ h_new_f32,               // [1024][64]
    unsigned short* __restrict__ h_new_bf16,     // base: +b*2048 +1024 +c
    float* __restrict__ xout_f32,                // [1024][64]
    unsigned short* __restrict__ xout_bf16) {    // base: +b*2048 +c (nullable)
  int lane = threadIdx.x & 63, w = threadIdx.x >> 6, quad = lane >> 4;
  int rt = blockIdx.x;
  int b = w * 16 + (lane & 15);
  const uint4* Bq = (const uint4*)xcat_in + (size_t)b * 256 + quad; // +ks*4
  const uint4* Arq = (const uint4*)Ar + (size_t)rt * 64 * 64 + lane;
  const uint4* Azq = (const uint4*)Az + (size_t)rt * 64 * 64 + lane;
  const uint4* Anq = (const uint4*)An + (size_t)rt * 64 * 64 + lane;
  f32x4 aR = {0.f, 0.f, 0.f, 0.f}, aZ = aR, aNI = aR, aNH = aR;
#pragma unroll 8
  for (int ks = 0; ks < 32; ++ks) {
    bf16x8 bf = __builtin_bit_cast(bf16x8, Bq[ks * 4]);
    aR = __builtin_amdgcn_mfma_f32_16x16x32_bf16(__builtin_bit_cast(bf16x8, Arq[ks * 64]), bf, aR, 0, 0, 0);
    aZ = __builtin_amdgcn_mfma_f32_16x16x32_bf16(__builtin_bit_cast(bf16x8, Azq[ks * 64]), bf, aZ, 0, 0, 0);
    aNI = __builtin_amdgcn_mfma_f32_16x16x32_bf16(__builtin_bit_cast(bf16x8, Anq[ks * 64]), bf, aNI, 0, 0, 0);
  }
#pragma unroll 8
  for (int ks = 32; ks < 64; ++ks) {
    bf16x8 bf = __builtin_bit_cast(bf16x8, Bq[ks * 4]);
    aR = __builtin_amdgcn_mfma_f32_16x16x32_bf16(__builtin_bit_cast(bf16x8, Arq[ks * 64]), bf, aR, 0, 0, 0);
    aZ = __builtin_amdgcn_mfma_f32_16x16x32_bf16(__builtin_bit_cast(bf16x8, Azq[ks * 64]), bf, aZ, 0, 0, 0);
    aNH = __builtin_amdgcn_mfma_f32_16x16x32_bf16(__builtin_bit_cast(bf16x8, Anq[ks * 64]), bf, aNH, 0, 0, 0);
  }
  int ch = rt * 16 + quad * 4;
#pragma unroll
  for (int i = 0; i < 4; ++i) {
    int c = ch + i;
    float r = sigm(aR[i] + bih[c] + bhh[c]);
    float z = sigm(aZ[i] + bih[kC + c] + bhh[kC + c]);
    float n = tanh_(aNI[i] + bih[2 * kC + c] + r * (aNH[i] + bhh[2 * kC + c]));
    float hold = h_old[c * kB + b];
    float hn = (1.0f - z) * n + z * hold;
    float xo = xin_f32[c * kB + b] + hn;
    h_new_f32[c * kB + b] = hn;
    h_new_bf16[(size_t)b * 2048 + 1024 + c] = f2bf(hn);
    xout_f32[c * kB + b] = xo;
    if (xout_bf16) xout_bf16[(size_t)b * 2048 + c] = f2bf(xo);
  }
}

// attention GRU: B = [feat(16 ks, fp32 from inputs) | p(4 ks) | h(32 ks)]; 52 ks.
__global__ __launch_bounds__(256) void k_attn_mfma(
    const unsigned short* __restrict__ Ar, const unsigned short* __restrict__ Az,
    const unsigned short* __restrict__ An,
    const float* __restrict__ inputs, int t,
    const unsigned short* __restrict__ p_bf16,   // [64][128]
    const unsigned short* __restrict__ h_bf16,   // xcat1[prev]: +b*2048 +k
    const float* __restrict__ h_old,             // [1024][64]
    const float* __restrict__ bih, const float* __restrict__ bhh,
    float* __restrict__ h_new_f32,               // [1024][64]
    unsigned short* __restrict__ h_new_bf16) {   // xcat1[cur]: +b*2048 +c
  int lane = threadIdx.x & 63, w = threadIdx.x >> 6, quad = lane >> 4;
  int rt = blockIdx.x;
  int b = w * 16 + (lane & 15);
  const float* fsrc = inputs + (size_t)b * (kT * kI) + (size_t)t * kI + quad * 8;
  const uint4* Pq = (const uint4*)(p_bf16 + (size_t)b * kH2) + quad;   // +ks*4
  const uint4* Hq = (const uint4*)(h_bf16 + (size_t)b * 2048) + quad;  // +ks*4
  const int NKS = 52;
  const uint4* Arq = (const uint4*)Ar + (size_t)rt * NKS * 64 + lane;
  const uint4* Azq = (const uint4*)Az + (size_t)rt * NKS * 64 + lane;
  const uint4* Anq = (const uint4*)An + (size_t)rt * NKS * 64 + lane;
  f32x4 aR = {0.f, 0.f, 0.f, 0.f}, aZ = aR, aNI = aR, aNH = aR;
#pragma unroll 4
  for (int ks = 0; ks < 16; ++ks) {  // feat: convert fp32 -> bf16 on the fly
    float4 f0 = *(const float4*)(fsrc + ks * 32);
    float4 f1 = *(const float4*)(fsrc + ks * 32 + 4);
    union { unsigned short us[8]; bf16x8 v; } u;
    u.us[0] = f2bf(f0.x); u.us[1] = f2bf(f0.y); u.us[2] = f2bf(f0.z); u.us[3] = f2bf(f0.w);
    u.us[4] = f2bf(f1.x); u.us[5] = f2bf(f1.y); u.us[6] = f2bf(f1.z); u.us[7] = f2bf(f1.w);
    aR = __builtin_amdgcn_mfma_f32_16x16x32_bf16(__builtin_bit_cast(bf16x8, Arq[ks * 64]), u.v, aR, 0, 0, 0);
    aZ = __builtin_amdgcn_mfma_f32_16x16x32_bf16(__builtin_bit_cast(bf16x8, Azq[ks * 64]), u.v, aZ, 0, 0, 0);
    aNI = __builtin_amdgcn_mfma_f32_16x16x32_bf16(__builtin_bit_cast(bf16x8, Anq[ks * 64]), u.v, aNI, 0, 0, 0);
  }
#pragma unroll
  for (int ks = 16; ks < 20; ++ks) {  // prenet p
    bf16x8 bf = __builtin_bit_cast(bf16x8, Pq[(ks - 16) * 4]);
    aR = __builtin_amdgcn_mfma_f32_16x16x32_bf16(__builtin_bit_cast(bf16x8, Arq[ks * 64]), bf, aR, 0, 0, 0);
    aZ = __builtin_amdgcn_mfma_f32_16x16x32_bf16(__builtin_bit_cast(bf16x8, Azq[ks * 64]), bf, aZ, 0, 0, 0);
    aNI = __builtin_amdgcn_mfma_f32_16x16x32_bf16(__builtin_bit_cast(bf16x8, Anq[ks * 64]), bf, aNI, 0, 0, 0);
  }
#pragma unroll 8
  for (int ks = 20; ks < 52; ++ks) {  // recurrent h
    bf16x8 bf = __builtin_bit_cast(bf16x8, Hq[(ks - 20) * 4]);
    aR = __builtin_amdgcn_mfma_f32_16x16x32_bf16(__builtin_bit_cast(bf16x8, Arq[ks * 64]), bf, aR, 0, 0, 0);
    aZ = __builtin_amdgcn_mfma_f32_16x16x32_bf16(__builtin_bit_cast(bf16x8, Azq[ks * 64]), bf, aZ, 0, 0, 0);
    aNH = __builtin_amdgcn_mfma_f32_16x16x32_bf16(__builtin_bit_cast(bf16x8, Anq[ks * 64]), bf, aNH, 0, 0, 0);
  }
  int ch = rt * 16 + quad * 4;
#pragma unroll
  for (int i = 0; i < 4; ++i) {
    int c = ch + i;
    float r = sigm(aR[i] + bih[c] + bhh[c]);
    float z = sigm(aZ[i] + bih[kC + c] + bhh[kC + c]);
    float n = tanh_(aNI[i] + bih[2 * kC + c] + r * (aNH[i] + bhh[2 * kC + c]));
    float hold = h_old[c * kB + b];
    float hn = (1.0f - z) * n + z * hold;
    h_new_f32[c * kB + b] = hn;
    h_new_bf16[(size_t)b * 2048 + c] = f2bf(hn);
  }
}

} // namespace

extern "C" void kernel_launch(void* const* d_in, const int* in_sizes, int n_in,
                              void* d_out, int out_size, void* d_ws, size_t ws_size,
                              hipStream_t stream) {
  const float* inputs   = (const float*)d_in[0];
  const float* pre_w0   = (const float*)d_in[1];
  const float* pre_b0   = (const float*)d_in[2];
  const float* pre_w1   = (const float*)d_in[3];
  const float* pre_b1   = (const float*)d_in[4];
  const float* attn_wih = (const float*)d_in[5];
  const float* attn_whh = (const float*)d_in[6];
  const float* attn_bih = (const float*)d_in[7];
  const float* attn_bhh = (const float*)d_in[8];
  const float* gru_wih  = (const float*)d_in[9];
  const float* gru_whh  = (const float*)d_in[10];
  const float* gru_bih  = (const float*)d_in[11];
  const float* gru_bhh  = (const float*)d_in[12];
  const float* proj_w   = (const float*)d_in[13];
  const float* proj_b   = (const float*)d_in[14];
  float* out = (float*)d_out;
  char* ws = (char*)d_ws;

  // ---- workspace layout (bytes) ----
  const size_t ATTN_MAT = (size_t)kC * 1664 * 2;  // 3,407,872
  const size_t RES_MAT  = (size_t)kC * 2048 * 2;  // 4,194,304
  size_t off = 0;
  unsigned short* Aattn[3]; // r, z, n
  for (int g = 0; g < 3; ++g) { Aattn[g] = (unsigned short*)(ws + off); off += ATTN_MAT; }
  unsigned short* Ares[2][3];
  for (int l = 0; l < 2; ++l)
    for (int g = 0; g < 3; ++g) { Ares[l][g] = (unsigned short*)(ws + off); off += RES_MAT; }
  size_t actBase = off;
  const size_t XC = (size_t)kB * 2048 * 2;        // one xcat buffer (bytes)
  unsigned short* xcat1 = (unsigned short*)(ws + off); off += 2 * XC;
  unsigned short* xcat2 = (unsigned short*)(ws + off); off += 2 * XC;
  unsigned short* p_bf16 = (unsigned short*)(ws + off); off += (size_t)kB * kH2 * 2;
  const size_t HB = (size_t)kC * kB;              // floats
  float* hA_f32 = (float*)(ws + off); off += 2 * HB * 4;
  float* h1_f32 = (float*)(ws + off); off += 2 * HB * 4;
  float* h2_f32 = (float*)(ws + off); off += 2 * HB * 4;
  float* x1_f32 = (float*)(ws + off); off += HB * 4;
  float* x2_f32 = (float*)(ws + off); off += HB * 4;
  float* h_pre  = (float*)(ws + off); off += (size_t)kH1 * kB * 4;
  if (off > ws_size) return;  // workspace too small: fail loud

  // ---- one-time per launch: repack weights into bf16 fragment order ----
  for (int g = 0; g < 3; ++g) {
    k_build_frags<<<16 * 52, 256, 0, stream>>>(attn_wih, 640, attn_whh, kC,
                                               g * kC, 640, 52, Aattn[g]);
  }
  for (int l = 0; l < 2; ++l) {
    const float* wih = gru_wih + (size_t)l * 3 * kC * kC;
    const float* whh = gru_whh + (size_t)l * 3 * kC * kC;
    for (int g = 0; g < 3; ++g) {
      k_build_frags<<<16 * 64, 256, 0, stream>>>(wih, kC, whh, kC,
                                                 g * kC, kC, 64, Ares[l][g]);
    }
  }
  hipMemsetAsync(ws + actBase, 0, off - actBase, stream);

  dim3 blk(64, 4, 1);
  const size_t XCe = (size_t)kB * 2048;  // xcat buffer in ushort elems

  for (int t = 0; t < kT; ++t) {
    int cur = t & 1, nxt = cur ^ 1;
    k_prenet0<<<kH1 / 4, blk, 0, stream>>>(out, t, pre_w0, pre_b0, h_pre);
    k_prenet1<<<kH2 / 4, blk, 0, stream>>>(h_pre, pre_w1, pre_b1, p_bf16);
    k_attn_mfma<<<64, 256, 0, stream>>>(Aattn[0], Aattn[1], Aattn[2],
        inputs, t, p_bf16,
        xcat1 + nxt * XCe,          // h bf16 (written at t-1 into "nxt" buf)
        hA_f32 + cur * HB, attn_bih, attn_bhh,
        hA_f32 + nxt * HB,
        xcat1 + cur * XCe);         // hA_new bf16 -> res1 input slot
    k_res_mfma<<<64, 256, 0, stream>>>(Ares[0][0], Ares[0][1], Ares[0][2],
        xcat1 + cur * XCe,
        hA_f32 + nxt * HB,          // residual input x (fp32, just written)
        h1_f32 + cur * HB, gru_bih, gru_bhh,
        h1_f32 + nxt * HB,
        xcat1 + nxt * XCe,          // h1_new bf16 -> next step's slot
        x1_f32,
        xcat2 + cur * XCe);         // x1 bf16 -> res2 input slot
    k_res_mfma<<<64, 256, 0, stream>>>(Ares[1][0], Ares[1][1], Ares[1][2],
        xcat2 + cur * XCe,
        x1_f32,
        h2_f32 + cur * HB, gru_bih + 3 * kC, gru_bhh + 3 * kC,
        h2_f32 + nxt * HB,
        xcat2 + nxt * XCe,
        x2_f32,
        nullptr);
    k_proj<<<kM / 4, blk, 0, stream>>>(x2_f32, proj_w, proj_b, out, t);
  }
}

// Round 3
// 24103.835 us; speedup vs baseline: 6.3394x; 2.4758x over previous
//
#include <hip/hip_runtime.h>
#include <cstddef>

// Decoder: B=64, T=512, I=512, H1=256, H2=128, C=1024, M=80, L=2
// Round 3: occupancy fix. GRU matmuls: grid = 64 rt x 4 batch-tiles = 256
// blocks, 8 waves/block each owning a K-chunk; LDS reduction + in-block gate
// epilogue. Proj via MFMA (bf16 x2). Prenet fused into one kernel with
// transposed weights. 5 kernels/step.

namespace {

constexpr int kB = 64, kT = 512, kI = 512, kH1 = 256, kH2 = 128, kC = 1024, kM = 80;

typedef __attribute__((ext_vector_type(8))) __bf16 bf16x8;
typedef __attribute__((ext_vector_type(4))) float f32x4;

__device__ __forceinline__ float sigm(float x) { return 1.0f / (1.0f + __expf(-x)); }
__device__ __forceinline__ float tanh_(float x) {
  float a = fabsf(x);
  float e = __expf(-2.0f * a);
  float r = (1.0f - e) / (1.0f + e);
  return copysignf(r, x);
}
__device__ __forceinline__ unsigned short f2bf(float x) {
  unsigned u = __builtin_bit_cast(unsigned, x);
  u += 0x7fffu + ((u >> 16) & 1u);   // RNE
  return (unsigned short)(u >> 16);
}
__device__ __forceinline__ bf16x8 asbf(uint4 v) { return __builtin_bit_cast(bf16x8, v); }

// ---- weight repack: fp32 [row][col] -> bf16 frag order [rt][ks][lane][8] ----
// row = row0 + rt*16 + (lane&15), k = ks*32 + (lane>>4)*8 + j. col<K1: srcA else srcB.
__global__ __launch_bounds__(256) void k_build_frags(
    const float* __restrict__ srcA, int ldA,
    const float* __restrict__ srcB, int ldB,
    int row0, int K1, int nks, int nrt, unsigned short* __restrict__ dst) {
  int idx = blockIdx.x * 256 + threadIdx.x;
  int lane = idx & 63;
  int ks = (idx >> 6) % nks;
  int rt = idx / (64 * nks);
  if (rt >= nrt) return;
  int row = row0 + rt * 16 + (lane & 15);
  int kk = ks * 32 + ((lane >> 4) & 3) * 8;
  const float* s = (kk < K1) ? (srcA + (size_t)row * ldA + kk)
                             : (srcB + (size_t)row * ldB + (kk - K1));
  unsigned short* d = dst + ((size_t)(rt * nks + ks) * 64 + lane) * 8;
#pragma unroll
  for (int j = 0; j < 8; ++j) d[j] = f2bf(s[j]);
}

// dst[c][r] = src[r][c]
__global__ __launch_bounds__(256) void k_transpose(const float* __restrict__ src,
    int R, int Ccols, float* __restrict__ dst) {
  int i = blockIdx.x * 256 + threadIdx.x;
  if (i >= R * Ccols) return;
  int r = i / Ccols, c = i % Ccols;
  dst[c * R + r] = src[r * Ccols + c];
}

// ---- fused prenet: feat->bf16 + Linear(80->256)+ReLU + Linear(256->128)+ReLU
// one block per batch element; transposed weights give coalesced lane loads.
__global__ __launch_bounds__(256) void k_prenet(
    const float* __restrict__ inputs, int t, const float* __restrict__ out_frames,
    const float* __restrict__ w0t, const float* __restrict__ b0,
    const float* __restrict__ w1t, const float* __restrict__ b1,
    unsigned short* __restrict__ xcat0_cur) {   // [64][1664]
  int b = blockIdx.x, tid = threadIdx.x;
  __shared__ float sfr[kM];
  __shared__ float sh[kH1];
  const float* feat = inputs + ((size_t)b * kT + t) * kI;
  unsigned short* dst = xcat0_cur + (size_t)b * 1664;
  float2 f2v = *(const float2*)(feat + tid * 2);
  dst[tid * 2] = f2bf(f2v.x);
  dst[tid * 2 + 1] = f2bf(f2v.y);
  if (tid < kM)
    sfr[tid] = (t > 0) ? out_frames[(size_t)b * kT * kM + (size_t)(t - 1) * kM + tid] : 0.0f;
  __syncthreads();
  float acc = b0[tid];
#pragma unroll 8
  for (int m = 0; m < kM; ++m) acc = fmaf(w0t[m * kH1 + tid], sfr[m], acc);
  sh[tid] = fmaxf(acc, 0.0f);
  __syncthreads();
  if (tid < kH2) {
    float a = b1[tid];
#pragma unroll 8
    for (int k = 0; k < kH1; ++k) a = fmaf(w1t[k * kH2 + tid], sh[k], a);
    dst[512 + tid] = f2bf(fmaxf(a, 0.0f));
  }
}

// ---- generic GRU cell kernel -----------------------------------------------
// grid = 64 rt * 4 bt blocks, 512 threads (8 waves). Wave w owns ks range
// [w*NKS/8, (w+1)*NKS/8). NB = ks boundary between W_ih (i_n) and W_hh (h_n).
// BROW = B row stride in uint4 (elems/8). LDS reduce + gate epilogue in-block.
template<int NKS, int NB, int BROW>
__global__ __launch_bounds__(512) void k_gru(
    const unsigned short* __restrict__ Ar, const unsigned short* __restrict__ Az,
    const unsigned short* __restrict__ An,
    const unsigned short* __restrict__ Bsrc,   // [64][BROW*8] bf16
    const float* __restrict__ h_old,           // [1024][64]
    const float* __restrict__ bih, const float* __restrict__ bhh,
    const float* __restrict__ xin_f32,         // nullable (attn)
    float* __restrict__ h_new_f32,
    unsigned short* __restrict__ h_bf16, int hStride,    // write h at [b*hStride + c]
    unsigned short* __restrict__ xout_bf16, int xStride, // nullable
    float* __restrict__ xout_f32) {            // nullable
  __shared__ float red[8 * 4 * 64 * 4];        // [w][acc][lane][4] = 32 KB
  int tid = threadIdx.x;
  int lane = tid & 63, w = tid >> 6, quad = lane >> 4;
  int rt = blockIdx.x >> 2;
  int bt = blockIdx.x & 3;
  int b = bt * 16 + (lane & 15);
  int s = (w * NKS) >> 3, e = ((w + 1) * NKS) >> 3;
  const uint4* Bq = (const uint4*)Bsrc + (size_t)b * BROW + quad;
  const uint4* Arq = (const uint4*)Ar + (size_t)rt * NKS * 64 + lane;
  const uint4* Azq = (const uint4*)Az + (size_t)rt * NKS * 64 + lane;
  const uint4* Anq = (const uint4*)An + (size_t)rt * NKS * 64 + lane;
  f32x4 aR = {0.f, 0.f, 0.f, 0.f}, aZ = aR, aNI = aR, aNH = aR;
  for (int ks = s; ks < e; ++ks) {
    bf16x8 bv = asbf(Bq[ks * 4]);
    aR = __builtin_amdgcn_mfma_f32_16x16x32_bf16(asbf(Arq[ks * 64]), bv, aR, 0, 0, 0);
    aZ = __builtin_amdgcn_mfma_f32_16x16x32_bf16(asbf(Azq[ks * 64]), bv, aZ, 0, 0, 0);
    if (ks < NB)
      aNI = __builtin_amdgcn_mfma_f32_16x16x32_bf16(asbf(Anq[ks * 64]), bv, aNI, 0, 0, 0);
    else
      aNH = __builtin_amdgcn_mfma_f32_16x16x32_bf16(asbf(Anq[ks * 64]), bv, aNH, 0, 0, 0);
  }
  *(f32x4*)(red + ((w * 4 + 0) * 64 + lane) * 4) = aR;
  *(f32x4*)(red + ((w * 4 + 1) * 64 + lane) * 4) = aZ;
  *(f32x4*)(red + ((w * 4 + 2) * 64 + lane) * 4) = aNI;
  *(f32x4*)(red + ((w * 4 + 3) * 64 + lane) * 4) = aNH;
  __syncthreads();
  if (w < 4) {
    int q = lane >> 4, bb = lane & 15;
    // output channel-in-tile c' = w*4 + q; source lane = w*16 + bb, reg = q
    float R = 0.f, Z = 0.f, NI = 0.f, NH = 0.f;
#pragma unroll
    for (int ww = 0; ww < 8; ++ww) {
      int base = (ww * 4 * 64 + w * 16 + bb) * 4 + q;
      R  += red[base];
      Z  += red[base + 64 * 4];
      NI += red[base + 2 * 64 * 4];
      NH += red[base + 3 * 64 * 4];
    }
    int c = rt * 16 + w * 4 + q;
    float r = sigm(R + bih[c] + bhh[c]);
    float z = sigm(Z + bih[kC + c] + bhh[kC + c]);
    float n = tanh_(NI + bih[2 * kC + c] + r * (NH + bhh[2 * kC + c]));
    float hold = h_old[c * kB + b];
    float hn = (1.0f - z) * n + z * hold;
    h_new_f32[c * kB + b] = hn;
    h_bf16[(size_t)b * hStride + c] = f2bf(hn);
    float xo = xin_f32 ? (xin_f32[c * kB + b] + hn) : hn;
    if (xout_bf16) xout_bf16[(size_t)b * xStride + c] = f2bf(xo);
    if (xout_f32) xout_f32[c * kB + b] = xo;
  }
}

// ---- projection via MFMA: out[b][t][c] = pb[c] + proj_w[c,:] . x2[b,:] ------
__global__ __launch_bounds__(512) void k_proj_mfma(
    const unsigned short* __restrict__ Ap,    // [5][32][64][8]
    const unsigned short* __restrict__ x2bf,  // [64][1024]
    const float* __restrict__ pb,
    float* __restrict__ out, int t) {
  __shared__ float red[8 * 64 * 4];
  int tid = threadIdx.x, lane = tid & 63, w = tid >> 6, quad = lane >> 4;
  int rt = blockIdx.x >> 2, bt = blockIdx.x & 3;
  int b = bt * 16 + (lane & 15);
  const uint4* Bq = (const uint4*)x2bf + (size_t)b * 128 + quad;
  const uint4* Aq = (const uint4*)Ap + (size_t)rt * 32 * 64 + lane;
  f32x4 acc = {0.f, 0.f, 0.f, 0.f};
#pragma unroll
  for (int ks = w * 4; ks < w * 4 + 4; ++ks)
    acc = __builtin_amdgcn_mfma_f32_16x16x32_bf16(asbf(Aq[ks * 64]), asbf(Bq[ks * 4]), acc, 0, 0, 0);
  *(f32x4*)(red + (w * 64 + lane) * 4) = acc;
  __syncthreads();
  if (w < 4) {
    int q = lane >> 4, bb = lane & 15;
    int c = rt * 16 + w * 4 + q;
    float s = 0.f;
#pragma unroll
    for (int ww = 0; ww < 8; ++ww) s += red[(ww * 64 + w * 16 + bb) * 4 + q];
    if (c < kM) out[(size_t)b * kT * kM + (size_t)t * kM + c] = s + pb[c];
  }
}

} // namespace

extern "C" void kernel_launch(void* const* d_in, const int* in_sizes, int n_in,
                              void* d_out, int out_size, void* d_ws, size_t ws_size,
                              hipStream_t stream) {
  const float* inputs   = (const float*)d_in[0];
  const float* pre_w0   = (const float*)d_in[1];
  const float* pre_b0   = (const float*)d_in[2];
  const float* pre_w1   = (const float*)d_in[3];
  const float* pre_b1   = (const float*)d_in[4];
  const float* attn_wih = (const float*)d_in[5];
  const float* attn_whh = (const float*)d_in[6];
  const float* attn_bih = (const float*)d_in[7];
  const float* attn_bhh = (const float*)d_in[8];
  const float* gru_wih  = (const float*)d_in[9];
  const float* gru_whh  = (const float*)d_in[10];
  const float* gru_bih  = (const float*)d_in[11];
  const float* gru_bhh  = (const float*)d_in[12];
  const float* proj_w   = (const float*)d_in[13];
  const float* proj_b   = (const float*)d_in[14];
  float* out = (float*)d_out;
  char* ws = (char*)d_ws;

  // ---- workspace layout ----
  const size_t ATTN_MAT = (size_t)64 * 52 * 64 * 8 * 2;  // 3,407,872 B
  const size_t RES_MAT  = (size_t)64 * 64 * 64 * 8 * 2;  // 4,194,304 B
  const size_t PROJ_MAT = (size_t)5 * 32 * 64 * 8 * 2;   // 163,840 B
  size_t off = 0;
  unsigned short* Aattn[3];
  for (int g = 0; g < 3; ++g) { Aattn[g] = (unsigned short*)(ws + off); off += ATTN_MAT; }
  unsigned short* Ares[2][3];
  for (int l = 0; l < 2; ++l)
    for (int g = 0; g < 3; ++g) { Ares[l][g] = (unsigned short*)(ws + off); off += RES_MAT; }
  unsigned short* Aproj = (unsigned short*)(ws + off); off += PROJ_MAT;
  float* w0t = (float*)(ws + off); off += (size_t)kM * kH1 * 4;
  float* w1t = (float*)(ws + off); off += (size_t)kH1 * kH2 * 4;
  size_t actBase = off;
  unsigned short* xcat0 = (unsigned short*)(ws + off); off += 2 * (size_t)kB * 1664 * 2;
  unsigned short* xcat1 = (unsigned short*)(ws + off); off += 2 * (size_t)kB * 2048 * 2;
  unsigned short* xcat2 = (unsigned short*)(ws + off); off += 2 * (size_t)kB * 2048 * 2;
  unsigned short* x2bf  = (unsigned short*)(ws + off); off += (size_t)kB * kC * 2;
  const size_t HB = (size_t)kC * kB;
  float* hA = (float*)(ws + off); off += 2 * HB * 4;
  float* h1 = (float*)(ws + off); off += 2 * HB * 4;
  float* h2 = (float*)(ws + off); off += 2 * HB * 4;
  float* x1 = (float*)(ws + off); off += HB * 4;
  if (off > ws_size) return;  // fail loud if workspace too small

  // ---- one-time per launch: weight repack + transposes + zero init ----
  for (int g = 0; g < 3; ++g)
    k_build_frags<<<16 * 52, 256, 0, stream>>>(attn_wih, 640, attn_whh, kC,
                                               g * kC, 640, 52, 64, Aattn[g]);
  for (int l = 0; l < 2; ++l) {
    const float* wih = gru_wih + (size_t)l * 3 * kC * kC;
    const float* whh = gru_whh + (size_t)l * 3 * kC * kC;
    for (int g = 0; g < 3; ++g)
      k_build_frags<<<16 * 64, 256, 0, stream>>>(wih, kC, whh, kC,
                                                 g * kC, kC, 64, 64, Ares[l][g]);
  }
  k_build_frags<<<5 * 32 / 4, 256, 0, stream>>>(proj_w, kC, proj_w, kC,
                                                0, kC, 32, 5, Aproj);
  k_transpose<<<(kH1 * kM + 255) / 256, 256, 0, stream>>>(pre_w0, kH1, kM, w0t);
  k_transpose<<<(kH2 * kH1 + 255) / 256, 256, 0, stream>>>(pre_w1, kH2, kH1, w1t);
  hipMemsetAsync(ws + actBase, 0, off - actBase, stream);

  const size_t X0 = (size_t)kB * 1664;  // xcat0 buffer elems
  const size_t XC = (size_t)kB * 2048;  // xcat1/2 buffer elems
  const float* g_bih1 = gru_bih + 3 * kC;
  const float* g_bhh1 = gru_bhh + 3 * kC;

  for (int t = 0; t < kT; ++t) {
    int cur = t & 1, nxt = cur ^ 1;
    k_prenet<<<kB, 256, 0, stream>>>(inputs, t, out, w0t, pre_b0, w1t, pre_b1,
                                     xcat0 + cur * X0);
    // attn GRU: B = xcat0[cur] (feat|p|h), h written into xcat0[nxt]+640 and
    // xcat1[cur] x-slot; fp32 h double-buffered in hA.
    k_gru<52, 20, 208><<<256, 512, 0, stream>>>(Aattn[0], Aattn[1], Aattn[2],
        xcat0 + cur * X0, hA + cur * HB, attn_bih, attn_bhh,
        nullptr, hA + nxt * HB,
        xcat0 + nxt * X0 + 640, 1664,
        xcat1 + cur * XC, 2048,
        nullptr);
    // res GRU 1: B = xcat1[cur] (x|h1); h1 -> xcat1[nxt]+1024; x1 -> xcat2[cur]
    k_gru<64, 32, 256><<<256, 512, 0, stream>>>(Ares[0][0], Ares[0][1], Ares[0][2],
        xcat1 + cur * XC, h1 + cur * HB, gru_bih, gru_bhh,
        hA + nxt * HB, h1 + nxt * HB,
        xcat1 + nxt * XC + 1024, 2048,
        xcat2 + cur * XC, 2048,
        x1);
    // res GRU 2: B = xcat2[cur] (x1|h2); h2 -> xcat2[nxt]+1024; x2 -> x2bf
    k_gru<64, 32, 256><<<256, 512, 0, stream>>>(Ares[1][0], Ares[1][1], Ares[1][2],
        xcat2 + cur * XC, h2 + cur * HB, g_bih1, g_bhh1,
        x1, h2 + nxt * HB,
        xcat2 + nxt * XC + 1024, 2048,
        x2bf, 1024,
        nullptr);
    k_proj_mfma<<<20, 512, 0, stream>>>(Aproj, x2bf, proj_b, out, t);
  }
}